// Round 1
// baseline (326.061 us; speedup 1.0000x reference)
//
#include <hip/hip_runtime.h>
#include <hip/hip_bf16.h>

// Problem constants
#define BB 4096
#define TT 16
#define HH 768
#define AA 128
#define VV 16
#define LL 2
#define NCHUNK 6        // K chunks of 128 (full K per block)
#define MT 16           // rows per tile (max tiles = 4096/16 + 15 = 271)

typedef __attribute__((ext_vector_type(8))) short short8v;   // 8 bf16 (4 VGPRs)
typedef __attribute__((ext_vector_type(4))) float float4v;   // MFMA C/D frag

__device__ __forceinline__ unsigned short f2bf(float f) {
    __hip_bfloat16 h = __float2bfloat16(f);   // RNE
    return *reinterpret_cast<unsigned short*>(&h);
}

__device__ __forceinline__ float gelu_tanh(float z) {
    float y = 0.7978845608028654f * (z + 0.044715f * z * z * z);
    y = fminf(fmaxf(y, -15.f), 15.f);
    float e = __expf(2.f * y);
    float th = (e - 1.f) / (e + 1.f);
    return 0.5f * z * (1.f + th);
}

// Single fused kernel. Each block is fully self-sufficient (no workspace, no
// second launch): it re-derives the bucketing, computes Wuc/buc for its own
// variety, transposes Wd chunks inline into LDS, then runs the MFMA pipeline.
__global__ __launch_bounds__(256) void k_fused(
    const float* __restrict__ last_hidden,
    const int*   __restrict__ variety_ids,
    const float* __restrict__ Wd,   // (V, H, A)
    const float* __restrict__ bd,   // (V, A)
    const float* __restrict__ Wu,   // (V, A, H)
    const float* __restrict__ bu,   // (V, H)
    const float* __restrict__ Wc,   // (L, H)
    const float* __restrict__ bc,   // (L,)
    float* __restrict__ out)        // (B, L)
{
    __shared__ __align__(16) unsigned short Xs[MT * 136];    // [row][k], pad 8
    __shared__ __align__(16) unsigned short Wds[128 * 136];  // [a][k] (reused: redbuf, p_part)
    __shared__ __align__(16) unsigned short WcB[16 * 136];   // side B tile
    __shared__ float Wuc_s[AA * LL];   // Wu[v] @ Wc^T
    __shared__ float buc_s[LL];        // bu[v] @ Wc^T
    __shared__ int   hist[VV];
    __shared__ int   srows[MT];
    __shared__ float xc[MT * LL];
    __shared__ int   scanw[4];

    const int t    = threadIdx.x;
    const int lane = t & 63;
    const int wid  = t >> 6;
    const int rt   = blockIdx.x;

    // ---------------- phase A: per-block histogram of variety_ids ----------
    int ids[16];
    {
        const int4* vp = reinterpret_cast<const int4*>(variety_ids) + t * 4;
        int4 A0 = vp[0], A1 = vp[1], A2 = vp[2], A3 = vp[3];
        ids[0]=A0.x; ids[1]=A0.y; ids[2]=A0.z; ids[3]=A0.w;
        ids[4]=A1.x; ids[5]=A1.y; ids[6]=A1.z; ids[7]=A1.w;
        ids[8]=A2.x; ids[9]=A2.y; ids[10]=A2.z; ids[11]=A2.w;
        ids[12]=A3.x; ids[13]=A3.y; ids[14]=A3.z; ids[15]=A3.w;
    }
    if (t < VV) hist[t] = 0;
    __syncthreads();
    {
        // packed per-thread counts: 4x uint64, 16-bit fields (v = word*4 + field)
        unsigned long long p0 = 0, p1 = 0, p2 = 0, p3 = 0;
        #pragma unroll
        for (int i = 0; i < 16; ++i) {
            int vv = ids[i];
            unsigned long long inc = 1ull << ((vv & 3) * 16);
            int w = vv >> 2;
            p0 += (w == 0) ? inc : 0ull;
            p1 += (w == 1) ? inc : 0ull;
            p2 += (w == 2) ? inc : 0ull;
            p3 += (w == 3) ? inc : 0ull;
        }
        #pragma unroll
        for (int d = 1; d < 64; d <<= 1) {
            p0 += __shfl_xor(p0, d);
            p1 += __shfl_xor(p1, d);
            p2 += __shfl_xor(p2, d);
            p3 += __shfl_xor(p3, d);
        }
        if (lane < VV) {
            int w = lane >> 2;
            unsigned long long pw = (w == 0) ? p0 : (w == 1) ? p1 : (w == 2) ? p2 : p3;
            int c = (int)((pw >> ((lane & 3) * 16)) & 0xffffull);
            if (c) atomicAdd(&hist[lane], c);
        }
    }
    __syncthreads();

    // ---------------- phase B: tile assignment (uniform) --------------------
    int v = -1, tloc = 0, cnt = 0;
    {
        int acc_t = 0;
        for (int vv = 0; vv < VV; ++vv) {
            int c  = hist[vv];
            int nt = (c + MT - 1) >> 4;
            if (v < 0 && rt < acc_t + nt) {
                v = vv; tloc = rt - acc_t;
                cnt = c - tloc * MT; if (cnt > MT) cnt = MT;
            }
            acc_t += nt;
        }
    }
    if (v < 0) return;   // surplus block (uniform exit)

    // ---------------- phase C: find this tile's rows (rank scan) ------------
    {
        int m_t = 0;
        #pragma unroll
        for (int i = 0; i < 16; ++i) m_t += (ids[i] == v) ? 1 : 0;
        int isc = m_t;
        #pragma unroll
        for (int d = 1; d < 64; d <<= 1) {
            int y = __shfl_up(isc, d);
            if (lane >= d) isc += y;
        }
        if (lane == 63) scanw[wid] = isc;
        __syncthreads();
        int base = 0;
        #pragma unroll
        for (int w = 0; w < 4; ++w) if (w < wid) base += scanw[w];
        int r = base + isc - m_t - tloc * MT;  // rel rank of my first match
        #pragma unroll
        for (int i = 0; i < 16; ++i) {
            if (ids[i] == v) {
                if (r >= 0 && r < MT) srows[r] = t * 16 + i;
                ++r;
            }
        }
    }
    __syncthreads();
    if (t == 0 && cnt < MT) {
        int last = srows[cnt - 1];
        for (int i = cnt; i < MT; ++i) srows[i] = last;
    }

    // ---------------- phase D: Wuc = Wu[v] @ Wc^T (128 x 2) -----------------
    {
        const int a    = t >> 1;       // 0..127
        const int half = t & 1;        // h-half of 384
        const float* wu  = Wu + ((size_t)v * AA + a) * HH + half * 384;
        const float* wcb = Wc + half * 384;
        float s0 = 0.f, s1 = 0.f;
        #pragma unroll 8
        for (int h = 0; h < 384; h += 4) {
            float4 w  = *(const float4*)(wu  + h);
            float4 c0 = *(const float4*)(wcb + h);
            float4 c1 = *(const float4*)(wcb + HH + h);
            s0 += w.x * c0.x + w.y * c0.y + w.z * c0.z + w.w * c0.w;
            s1 += w.x * c1.x + w.y * c1.y + w.z * c1.z + w.w * c1.w;
        }
        s0 += __shfl_xor(s0, 1);
        s1 += __shfl_xor(s1, 1);
        if (half == 0) { Wuc_s[a * LL + 0] = s0; Wuc_s[a * LL + 1] = s1; }
    }

    // ---------------- phase E: buc = bu[v] @ Wc^T (2) -----------------------
    {
        float* redbuf = (float*)Wds;   // 256 floats, Wds not yet in use
        if (t < 128) {
            const float* bv = bu + (size_t)v * HH + t * 6;
            const float* c0 = Wc + t * 6;
            const float* c1 = Wc + HH + t * 6;
            float s0 = 0.f, s1 = 0.f;
            #pragma unroll
            for (int j = 0; j < 6; ++j) { s0 += bv[j] * c0[j]; s1 += bv[j] * c1[j]; }
            redbuf[t] = s0; redbuf[128 + t] = s1;
        }
        __syncthreads();
        if (wid == 0) {
            float s0 = redbuf[lane] + redbuf[lane + 64];
            float s1 = redbuf[128 + lane] + redbuf[192 + lane];
            #pragma unroll
            for (int d = 32; d; d >>= 1) { s0 += __shfl_xor(s0, d); s1 += __shfl_xor(s1, d); }
            if (lane == 0) { buc_s[0] = s0; buc_s[1] = s1; }
        }
    }

    // ---------------- main MFMA loop ----------------------------------------
    const int wv_ = wid;               // 0..3: a-quarter
    const int ac0 = wv_ * 32;
    const int m = lane & 15, quad = lane >> 4;

    float4v acc[2];                    // a-cols ac0 + j*16 + m
    float4v accx;                      // classifier side (wave 0)
    acc[0] = (float4v){0.f, 0.f, 0.f, 0.f};
    acc[1] = (float4v){0.f, 0.f, 0.f, 0.f};
    accx   = (float4v){0.f, 0.f, 0.f, 0.f};

    const float* wdv = Wd + (size_t)v * HH * AA;

    for (int kc = 0; kc < NCHUNK; ++kc) {
        const int ks0 = kc * 128;
        __syncthreads();
        // stage X: 16 rows x 128 k, fp32 -> bf16 (512 float4 granules)
        #pragma unroll
        for (int s = 0; s < 2; ++s) {
            int idx = t + s * 256;        // 0..511
            int r   = idx >> 5;
            int k4  = idx & 31;
            const float* xr = last_hidden + (size_t)srows[r] * TT * HH + ks0 + k4 * 4;
            float4 xv = *(const float4*)xr;
            unsigned int q0 = (unsigned)f2bf(xv.x) | ((unsigned)f2bf(xv.y) << 16);
            unsigned int q1 = (unsigned)f2bf(xv.z) | ((unsigned)f2bf(xv.w) << 16);
            *(uint2*)&Xs[r * 136 + k4 * 4] = make_uint2(q0, q1);
        }
        // stage Wd chunk inline: global [k][a] fp32 -> LDS [a][k] bf16 (pad 136)
        #pragma unroll
        for (int s = 0; s < 16; ++s) {
            int idx = t + s * 256;        // 0..4095
            int hl  = idx >> 5;           // 0..127 (k within chunk)
            int a4  = idx & 31;           // float4 granule along a
            float4 wv = *(const float4*)(wdv + (size_t)(ks0 + hl) * AA + a4 * 4);
            Wds[(a4 * 4 + 0) * 136 + hl] = f2bf(wv.x);
            Wds[(a4 * 4 + 1) * 136 + hl] = f2bf(wv.y);
            Wds[(a4 * 4 + 2) * 136 + hl] = f2bf(wv.z);
            Wds[(a4 * 4 + 3) * 136 + hl] = f2bf(wv.w);
        }
        // stage WcB: 16 cols x 128 k; col 0/1 = Wc row, cols 2..15 = 0
        {
            int c = t >> 4, g = t & 15;   // 256 granules of 8
            uint4 w = make_uint4(0u, 0u, 0u, 0u);
            if (c < LL) {
                const float* wcr = Wc + (size_t)c * HH + ks0 + g * 8;
                float4 w0 = *(const float4*)wcr;
                float4 w1 = *(const float4*)(wcr + 4);
                w.x = (unsigned)f2bf(w0.x) | ((unsigned)f2bf(w0.y) << 16);
                w.y = (unsigned)f2bf(w0.z) | ((unsigned)f2bf(w0.w) << 16);
                w.z = (unsigned)f2bf(w1.x) | ((unsigned)f2bf(w1.y) << 16);
                w.w = (unsigned)f2bf(w1.z) | ((unsigned)f2bf(w1.w) << 16);
            }
            *(uint4*)&WcB[c * 136 + g * 8] = w;
        }
        __syncthreads();

        #pragma unroll
        for (int k0 = 0; k0 < 128; k0 += 32) {
            short8v af  = *(const short8v*)&Xs[m * 136 + k0 + quad * 8];
            short8v bf0 = *(const short8v*)&Wds[(ac0 + m) * 136 + k0 + quad * 8];
            short8v bf1 = *(const short8v*)&Wds[(ac0 + 16 + m) * 136 + k0 + quad * 8];
            acc[0] = __builtin_amdgcn_mfma_f32_16x16x32_bf16(af, bf0, acc[0], 0, 0, 0);
            acc[1] = __builtin_amdgcn_mfma_f32_16x16x32_bf16(af, bf1, acc[1], 0, 0, 0);
            if (wv_ == 0) {
                short8v cf = *(const short8v*)&WcB[m * 136 + k0 + quad * 8];
                accx = __builtin_amdgcn_mfma_f32_16x16x32_bf16(af, cf, accx, 0, 0, 0);
            }
        }
    }

    __syncthreads();   // all waves done reading Wds; reuse as p_part
    float* p_part = (float*)Wds;   // [row][l][slot], slot = wv_*16 + m (64 slots)

    // epilogue: z += bd -> gelu -> per-lane partial of sum_a h*Wuc
    {
        float bdv[2], w0v[2], w1v[2];
        #pragma unroll
        for (int j = 0; j < 2; ++j) {
            int a = ac0 + j * 16 + m;
            bdv[j] = bd[v * AA + a];
            w0v[j] = Wuc_s[a * LL + 0];
            w1v[j] = Wuc_s[a * LL + 1];
        }
        #pragma unroll
        for (int reg = 0; reg < 4; ++reg) {
            int row = quad * 4 + reg;
            float p0 = 0.f, p1 = 0.f;
            #pragma unroll
            for (int j = 0; j < 2; ++j) {
                float h = gelu_tanh(acc[j][reg] + bdv[j]);
                p0 += h * w0v[j];
                p1 += h * w1v[j];
            }
            p_part[(row * LL + 0) * 64 + wv_ * 16 + m] = p0;
            p_part[(row * LL + 1) * 64 + wv_ * 16 + m] = p1;
        }
        // classifier side-block: col m (<2) of accx is logit l = m
        if (wv_ == 0 && m < LL) {
            #pragma unroll
            for (int reg = 0; reg < 4; ++reg) {
                int row = quad * 4 + reg;
                xc[row * LL + m] = accx[reg];
            }
        }
    }
    __syncthreads();

    // final: one thread per (row, l)
    if (t < MT * LL) {
        int row = t >> 1, l = t & 1;
        if (row < cnt) {
            float s = 0.f;
            #pragma unroll
            for (int k = 0; k < 64; ++k) s += p_part[(row * LL + l) * 64 + k];
            int gr = srows[row];
            out[(size_t)gr * LL + l] = s + xc[row * LL + l] + buc_s[l] + bc[l];
        }
    }
}

extern "C" void kernel_launch(void* const* d_in, const int* in_sizes, int n_in,
                              void* d_out, int out_size, void* d_ws, size_t ws_size,
                              hipStream_t stream) {
    const float* last_hidden = (const float*)d_in[0];
    const int*   variety_ids = (const int*)d_in[2];
    const float* Wd = (const float*)d_in[3];
    const float* bd = (const float*)d_in[4];
    const float* Wu = (const float*)d_in[5];
    const float* bu = (const float*)d_in[6];
    const float* Wc = (const float*)d_in[7];
    const float* bc = (const float*)d_in[8];
    float* out = (float*)d_out;

    // single fused launch: no workspace, no inter-kernel drain
    k_fused<<<271, 256, 0, stream>>>(last_hidden, variety_ids, Wd, bd, Wu, bu, Wc, bc, out);
}

// Round 2
// 267.507 us; speedup vs baseline: 1.2189x; 1.2189x over previous
//
#include <hip/hip_runtime.h>
#include <hip/hip_bf16.h>

// Problem constants
#define BB 4096
#define TT 16
#define HH 768
#define AA 128
#define VV 16
#define LL 2
#define NCHUNK 6        // K chunks of 128 (full K per block)
#define MT 16           // rows per tile (parallelism: up to 271 blocks)

typedef __attribute__((ext_vector_type(8))) short short8v;   // 8 bf16 (4 VGPRs)
typedef __attribute__((ext_vector_type(4))) float float4v;   // MFMA C/D frag

// ws layout (int indices into d_ws):
//  [0..16]       offs (int)     bucket offsets
//  [64..4159]    rows (int)     bucketed row ids
//  [4160..8255]  Wuc  (float)   [V][A][L] = Wu@Wc^T
//  [8256..8287]  buc  (float)   [V][L]    = bu@Wc^T
//  [8448..]      Wdp  (ushort)  [V][6][A][128] bf16 transposed Wd (dense)
#define WS_OFFS 0
#define WS_ROWS 64
#define WS_WUC  4160
#define WS_BUC  8256
#define WS_WDP  8448

__device__ __forceinline__ unsigned short f2bf(float f) {
    __hip_bfloat16 h = __float2bfloat16(f);   // RNE
    return *reinterpret_cast<unsigned short*>(&h);
}

__device__ __forceinline__ float gelu_tanh(float z) {
    float y = 0.7978845608028654f * (z + 0.044715f * z * z * z);
    y = fminf(fmaxf(y, -15.f), 15.f);
    float e = __expf(2.f * y);
    float th = (e - 1.f) / (e + 1.f);
    return 0.5f * z * (1.f + th);
}

// ---------------- K1: prep (verbatim from the verified 271 µs version)
// blocks 0..95    : Wdp[v][kc] = bf16 transpose of Wd chunk
// blocks 96..223  : Wuc — 128 blocks, 16 a-columns each (16 thr/col)
// block 224       : buc[v][l] = bu[v] @ Wc^T
// block 225       : bucket rows by variety
__global__ __launch_bounds__(256) void k_prep(
    const int*   __restrict__ variety_ids,
    const float* __restrict__ Wd,   // (V, H, A)
    const float* __restrict__ Wu,   // (V, A, H)
    const float* __restrict__ bu,   // (V, H)
    const float* __restrict__ Wc,   // (L, H)
    int* __restrict__ ws_i)
{
    __shared__ __align__(16) unsigned short Wds[128 * 136];
    __shared__ float sp0[256], sp1[256];
    __shared__ int hist[VV], hoff[VV + 1], hcur[VV];

    const int t = threadIdx.x;
    const int bid = blockIdx.x;
    unsigned short* wdp = (unsigned short*)(ws_i + WS_WDP);
    float* Wuc = (float*)(ws_i + WS_WUC);
    float* buc = (float*)(ws_i + WS_BUC);

    if (bid < 96) {
        // ---- Wd chunk transpose + convert: global [k][a] -> [a][k] ----
        const int v = bid / NCHUNK, kc = bid % NCHUNK;
        const float* wd = Wd + (size_t)v * HH * AA;
        const int ks0 = kc * 128;
        #pragma unroll
        for (int s = 0; s < 16; ++s) {
            int idx = t + s * 256;
            int hl  = idx >> 5;
            int a4  = idx & 31;
            float4 wv = *(const float4*)(wd + (size_t)(ks0 + hl) * AA + a4 * 4);
            Wds[(a4 * 4 + 0) * 136 + hl] = f2bf(wv.x);
            Wds[(a4 * 4 + 1) * 136 + hl] = f2bf(wv.y);
            Wds[(a4 * 4 + 2) * 136 + hl] = f2bf(wv.z);
            Wds[(a4 * 4 + 3) * 136 + hl] = f2bf(wv.w);
        }
        __syncthreads();
        unsigned short* dst = wdp + (size_t)(v * NCHUNK + kc) * AA * 128;
        #pragma unroll
        for (int s = 0; s < 8; ++s) {
            int G = t + s * 256;            // 0..2047
            int a = G >> 4, g = G & 15;     // 16 granules of 8 bf16 per row
            uint4 w = *(const uint4*)&Wds[a * 136 + g * 8];
            *(uint4*)&dst[a * 128 + g * 8] = w;
        }
    } else if (bid < 224) {
        // ---- Wuc: block handles (v, 16-a group); 16 threads per column ----
        const int v = (bid - 96) >> 3;
        const int g = (bid - 96) & 7;
        const int a_loc = t >> 4;           // 0..15
        const int q     = t & 15;           // h segment
        const int a = g * 16 + a_loc;
        const float* wu = Wu + (size_t)v * AA * HH + (size_t)a * HH;
        float s0 = 0.f, s1 = 0.f;
        #pragma unroll 4
        for (int h = q * 48; h < q * 48 + 48; h += 4) {
            float4 w  = *(const float4*)&wu[h];
            float4 c0 = *(const float4*)&Wc[h];
            float4 c1 = *(const float4*)&Wc[HH + h];
            s0 += w.x * c0.x + w.y * c0.y + w.z * c0.z + w.w * c0.w;
            s1 += w.x * c1.x + w.y * c1.y + w.z * c1.z + w.w * c1.w;
        }
        sp0[a_loc * 16 + q] = s0;
        sp1[a_loc * 16 + q] = s1;
        __syncthreads();
        if (t < 16) {
            float r0 = 0.f, r1 = 0.f;
            #pragma unroll
            for (int i = 0; i < 16; ++i) { r0 += sp0[t * 16 + i]; r1 += sp1[t * 16 + i]; }
            int aa = g * 16 + t;
            Wuc[(v * AA + aa) * LL + 0] = r0;
            Wuc[(v * AA + aa) * LL + 1] = r1;
        }
    } else if (bid == 224) {
        // ---- buc[v][l] : 32 pairs x 8 h-segments ----
        const int pair = t >> 3, seg = t & 7;
        const int v = pair >> 1, l = pair & 1;
        float s = 0.f;
        const float* bv = bu + (size_t)v * HH;
        for (int h = seg * 96; h < seg * 96 + 96; ++h) s += bv[h] * Wc[l * HH + h];
        sp0[t] = s;
        __syncthreads();
        if (t < 32) {
            float r = 0.f;
            #pragma unroll
            for (int i = 0; i < 8; ++i) r += sp0[t * 8 + i];
            buc[t] = r;   // t = v*2 + l
        }
    } else {
        // ---- bucketing ----
        if (t < VV) hist[t] = 0;
        __syncthreads();
        for (int b = t; b < BB; b += 256) atomicAdd(&hist[variety_ids[b]], 1);
        __syncthreads();
        if (t == 0) {
            int s = 0;
            for (int i = 0; i < VV; ++i) { hoff[i] = s; s += hist[i]; }
            hoff[VV] = s;
            for (int i = 0; i <= VV; ++i) ws_i[WS_OFFS + i] = hoff[i];
        }
        __syncthreads();
        if (t < VV) hcur[t] = hoff[t];
        __syncthreads();
        for (int b = t; b < BB; b += 256) {
            int v = variety_ids[b];
            int p = atomicAdd(&hcur[v], 1);
            ws_i[WS_ROWS + p] = b;
        }
    }
}

// ---------------- K2: fused main — B-fragments direct from global (Wdp is
// already in fragment layout [a][k]), software-pipelined one chunk ahead.
// Single barrier per chunk; X double-buffered in LDS; no Wd/Wc LDS staging.
__global__ __launch_bounds__(256) void k_main(
    const float* __restrict__ last_hidden,
    const int*   __restrict__ ws_i,
    const float* __restrict__ bd,   // (V, A)
    const float* __restrict__ Wc,   // (L, H)
    const float* __restrict__ bc,   // (L,)
    float* __restrict__ out)        // (B, L)
{
    __shared__ __align__(16) unsigned short Xs[2][MT * 136];  // double-buffered A tile
    __shared__ __align__(16) float p_part[MT * LL * 64];      // 8 KB partials
    __shared__ int srows[MT];
    __shared__ float xc[MT * LL];

    const int* offs = ws_i + WS_OFFS;
    const int* rows = ws_i + WS_ROWS;
    const float* Wuc = (const float*)(ws_i + WS_WUC);
    const float* buc = (const float*)(ws_i + WS_BUC);
    const unsigned short* wdp = (const unsigned short*)(ws_i + WS_WDP);
    const int t = threadIdx.x;

    // tile -> (variety, local tile)
    const int rt = blockIdx.x;
    int v = -1, tloc = 0, cnt = 0, obase = 0, acc_t = 0;
    for (int vv = 0; vv < VV; ++vv) {
        int c  = offs[vv + 1] - offs[vv];
        int nt = (c + MT - 1) / MT;
        if (rt < acc_t + nt) {
            v = vv; tloc = rt - acc_t;
            cnt = c - tloc * MT; if (cnt > MT) cnt = MT;
            obase = offs[vv];
            break;
        }
        acc_t += nt;
    }
    if (v < 0) return;

    if (t < MT) {
        int rr = t < cnt ? t : cnt - 1;
        srows[t] = rows[obase + tloc * MT + rr];
    }
    __syncthreads();

    const int lane = t & 63;
    const int wv_  = t >> 6;              // 0..3: a-quarter
    const int ac0  = wv_ * 32;
    const int m = lane & 15, quad = lane >> 4;
    const int r0 = t >> 5, k4 = t & 31;   // X staging assignment (2 rows/thread)

    // per-lane base pointers
    const float* xb0 = last_hidden + (size_t)srows[r0]     * TT * HH + k4 * 4;
    const float* xb1 = last_hidden + (size_t)srows[r0 + 8] * TT * HH + k4 * 4;
    const unsigned short* wdv = wdp + (size_t)v * NCHUNK * AA * 128;
    const unsigned short* bp0 = wdv + (size_t)(ac0 + m)      * 128 + quad * 8;
    const unsigned short* bp1 = wdv + (size_t)(ac0 + 16 + m) * 128 + quad * 8;
    const float* cfp = Wc + (size_t)m * HH + quad * 8;   // only used when wv_==0 && m<LL

    float4v acc[2];                        // a-cols ac0 + j*16 + m
    float4v accx;                          // classifier side (wave 0)
    acc[0] = (float4v){0.f, 0.f, 0.f, 0.f};
    acc[1] = (float4v){0.f, 0.f, 0.f, 0.f};
    accx   = (float4v){0.f, 0.f, 0.f, 0.f};

    // prologue: issue chunk 0 loads (X rows + B fragments)
    float4 xA = *(const float4*)xb0;
    float4 xB = *(const float4*)xb1;
    short8v Bn[8];
    #pragma unroll
    for (int i = 0; i < 4; ++i) {
        Bn[i]     = *(const short8v*)(bp0 + i * 32);
        Bn[4 + i] = *(const short8v*)(bp1 + i * 32);
    }

    #pragma unroll
    for (int kc = 0; kc < NCHUNK; ++kc) {
        // rotate pipeline registers (SSA renames under full unroll)
        float4 xAc = xA, xBc = xB;
        short8v Bc[8];
        #pragma unroll
        for (int i = 0; i < 8; ++i) Bc[i] = Bn[i];

        // issue next-chunk loads BEFORE the barrier (stay in flight across it)
        if (kc + 1 < NCHUNK) {
            xA = *(const float4*)(xb0 + (kc + 1) * 128);
            xB = *(const float4*)(xb1 + (kc + 1) * 128);
            #pragma unroll
            for (int i = 0; i < 4; ++i) {
                Bn[i]     = *(const short8v*)(bp0 + (size_t)(kc + 1) * AA * 128 + i * 32);
                Bn[4 + i] = *(const short8v*)(bp1 + (size_t)(kc + 1) * AA * 128 + i * 32);
            }
        }

        // stage X(kc): cvt fp32->bf16, write to Xs[kc&1]
        unsigned short* xs = (unsigned short*)Xs[kc & 1];
        {
            unsigned int q0 = (unsigned)f2bf(xAc.x) | ((unsigned)f2bf(xAc.y) << 16);
            unsigned int q1 = (unsigned)f2bf(xAc.z) | ((unsigned)f2bf(xAc.w) << 16);
            *(uint2*)&xs[r0 * 136 + k4 * 4] = make_uint2(q0, q1);
            q0 = (unsigned)f2bf(xBc.x) | ((unsigned)f2bf(xBc.y) << 16);
            q1 = (unsigned)f2bf(xBc.z) | ((unsigned)f2bf(xBc.w) << 16);
            *(uint2*)&xs[(r0 + 8) * 136 + k4 * 4] = make_uint2(q0, q1);
        }
        __syncthreads();   // single barrier per chunk (double-buffered Xs)

        // classifier B-frags: wave 0, lanes m<2 read L2-hot Wc (fp32)
        float4 cfa[8];
        if (wv_ == 0 && m < LL) {
            #pragma unroll
            for (int i = 0; i < 4; ++i) {
                cfa[2 * i]     = *(const float4*)(cfp + kc * 128 + i * 32);
                cfa[2 * i + 1] = *(const float4*)(cfp + kc * 128 + i * 32 + 4);
            }
        }

        #pragma unroll
        for (int i = 0; i < 4; ++i) {
            short8v af = *(const short8v*)&xs[m * 136 + i * 32 + quad * 8];
            acc[0] = __builtin_amdgcn_mfma_f32_16x16x32_bf16(af, Bc[i],     acc[0], 0, 0, 0);
            acc[1] = __builtin_amdgcn_mfma_f32_16x16x32_bf16(af, Bc[4 + i], acc[1], 0, 0, 0);
            if (wv_ == 0) {
                short8v cf = (short8v){0, 0, 0, 0, 0, 0, 0, 0};
                if (m < LL) {
                    float4 c0 = cfa[2 * i], c1 = cfa[2 * i + 1];
                    cf[0] = (short)f2bf(c0.x); cf[1] = (short)f2bf(c0.y);
                    cf[2] = (short)f2bf(c0.z); cf[3] = (short)f2bf(c0.w);
                    cf[4] = (short)f2bf(c1.x); cf[5] = (short)f2bf(c1.y);
                    cf[6] = (short)f2bf(c1.z); cf[7] = (short)f2bf(c1.w);
                }
                accx = __builtin_amdgcn_mfma_f32_16x16x32_bf16(af, cf, accx, 0, 0, 0);
            }
        }
    }

    // epilogue: z += bd -> gelu -> per-lane partial of sum_a h*Wuc
    {
        float bdv[2], w0v[2], w1v[2];
        #pragma unroll
        for (int j = 0; j < 2; ++j) {
            int a = ac0 + j * 16 + m;
            bdv[j] = bd[v * AA + a];
            w0v[j] = Wuc[(v * AA + a) * LL + 0];
            w1v[j] = Wuc[(v * AA + a) * LL + 1];
        }
        #pragma unroll
        for (int reg = 0; reg < 4; ++reg) {
            int row = quad * 4 + reg;
            float p0 = 0.f, p1 = 0.f;
            #pragma unroll
            for (int j = 0; j < 2; ++j) {
                float h = gelu_tanh(acc[j][reg] + bdv[j]);
                p0 += h * w0v[j];
                p1 += h * w1v[j];
            }
            p_part[(row * LL + 0) * 64 + wv_ * 16 + m] = p0;
            p_part[(row * LL + 1) * 64 + wv_ * 16 + m] = p1;
        }
        // classifier side-block: col m (<2) of accx is logit l = m
        if (wv_ == 0 && m < LL) {
            #pragma unroll
            for (int reg = 0; reg < 4; ++reg) {
                int row = quad * 4 + reg;
                xc[row * LL + m] = accx[reg];
            }
        }
    }
    __syncthreads();

    // final: one thread per (row, l)
    if (t < MT * LL) {
        int row = t >> 1, l = t & 1;
        if (row < cnt) {
            float s = 0.f;
            #pragma unroll
            for (int k = 0; k < 64; ++k) s += p_part[(row * LL + l) * 64 + k];
            int gr = srows[row];
            out[(size_t)gr * LL + l] = s + xc[row * LL + l] + buc[v * LL + l] + bc[l];
        }
    }
}

extern "C" void kernel_launch(void* const* d_in, const int* in_sizes, int n_in,
                              void* d_out, int out_size, void* d_ws, size_t ws_size,
                              hipStream_t stream) {
    const float* last_hidden = (const float*)d_in[0];
    const int*   variety_ids = (const int*)d_in[2];
    const float* Wd = (const float*)d_in[3];
    const float* bd = (const float*)d_in[4];
    const float* Wu = (const float*)d_in[5];
    const float* bu = (const float*)d_in[6];
    const float* Wc = (const float*)d_in[7];
    const float* bc = (const float*)d_in[8];
    float* out = (float*)d_out;

    int* ws_i = (int*)d_ws;

    k_prep<<<226, 256, 0, stream>>>(variety_ids, Wd, Wu, bu, Wc, ws_i);
    // max tiles = sum_v ceil(cnt_v/16) <= 4096/16 + 15 = 271
    k_main<<<271, 256, 0, stream>>>(last_hidden, ws_i, bd, Wc, bc, out);
}